// Round 6
// baseline (161.362 us; speedup 1.0000x reference)
//
#include <hip/hip_runtime.h>
#include <hip/hip_bf16.h>

typedef __bf16 bf16_t;
typedef __bf16 bf16x8 __attribute__((ext_vector_type(8)));
typedef __bf16 bf16x4 __attribute__((ext_vector_type(4)));
typedef float f32x4 __attribute__((ext_vector_type(4)));

#define FDIM 512
#define BM 32
#define NTHR 256

// Kernel 1: Qt[g][f] = bf16(Q[f][g]) via LDS-tiled transpose (coalesced both sides)
__global__ void qtrans_kernel(const float* __restrict__ Q, bf16_t* __restrict__ Qt) {
    __shared__ float t[32][33];
    int tx = threadIdx.x & 31;
    int ty = threadIdx.x >> 5;
    int f0 = blockIdx.x * 32;
    int g0 = blockIdx.y * 32;
#pragma unroll
    for (int i = 0; i < 4; ++i)
        t[ty + 8 * i][tx] = Q[(size_t)(f0 + ty + 8 * i) * FDIM + g0 + tx];
    __syncthreads();
#pragma unroll
    for (int i = 0; i < 4; ++i)
        Qt[(size_t)(g0 + ty + 8 * i) * FDIM + f0 + tx] = (bf16_t)t[tx][ty + 8 * i];
}

// Kernel 2: fused  out[b] = sum_g (x Q)[b,g] * x[b,g]
// 256 threads = 4 waves, BM=32 rows/block, 4 blocks/CU (33 KB LDS) so that
// staging (HBM) of some blocks overlaps compute (LDS/MFMA) of others.
// Wave w owns col-pairs {w, w+4, 11-w, 15-w} -> 34 K-steps/wave, balanced.
__global__ __launch_bounds__(NTHR, 4) void bilinear_kernel(
    const float* __restrict__ x, const bf16_t* __restrict__ Qt,
    float* __restrict__ out)
{
    __shared__ bf16_t xs[BM * FDIM];   // 32 KB, XOR-swizzled: e ^= (row&15)<<3
    __shared__ float rsum[4][BM];      // per-wave row partials

    const int tid = threadIdx.x;
    const size_t blk = (size_t)blockIdx.x * BM;
    const float4* xin = (const float4*)(x + blk * FDIM);

    // ---- stage x: 16 float4/thread in 4 batches of 4 (max 16 payload VGPRs) ----
#pragma unroll 1
    for (int it = 0; it < 4; ++it) {
        float4 vv[4];
#pragma unroll
        for (int j = 0; j < 4; ++j) vv[j] = xin[(it * 4 + j) * NTHR + tid];
#pragma unroll
        for (int j = 0; j < 4; ++j) {
            int e = ((it * 4 + j) * NTHR + tid) * 4;
            int row = e >> 9;
            int se = e ^ ((row & 15) << 3);   // 16-slot spread, 8B-granular
            bf16x4 b;
            b[0] = (bf16_t)vv[j].x; b[1] = (bf16_t)vv[j].y;
            b[2] = (bf16_t)vv[j].z; b[3] = (bf16_t)vv[j].w;
            *(bf16x4*)(xs + se) = b;
        }
        __builtin_amdgcn_sched_barrier(0);  // keep batches separate (no hoist)
    }
    __syncthreads();

    const int w   = tid >> 6;
    const int l   = tid & 63;
    const int col = l & 15;   // A-frag row / B-frag col / D col
    const int kg  = l >> 4;   // k-group

    float rs[2][4];
#pragma unroll
    for (int m = 0; m < 2; ++m)
#pragma unroll
        for (int j = 0; j < 4; ++j) rs[m][j] = 0.0f;

    // 4 pairs/wave: {w, w+4, 11-w, 15-w}; nk = p+1 (triangle skip)
#pragma unroll 1
    for (int pi = 0; pi < 4; ++pi) {
        const int p  = (pi == 0) ? w : (pi == 1) ? (w + 4) : (pi == 2) ? (11 - w) : (15 - w);
        const int c0 = p * 32;
        const int nk = p + 1;

        f32x4 acc[2][2];   // [col-half][row-tile]
#pragma unroll
        for (int n = 0; n < 2; ++n)
#pragma unroll
            for (int m = 0; m < 2; ++m)
#pragma unroll
                for (int j = 0; j < 4; ++j) acc[n][m][j] = 0.0f;

        // B-frags: Qt[(c0+col)][kg*8 + ks*32 ...], contiguous 16B per lane
        const bf16_t* qb0 = Qt + (size_t)(c0 + col) * FDIM + kg * 8;
        const bf16_t* qb1 = qb0 + 16 * FDIM;
        bf16x8 b0 = *(const bf16x8*)(qb0);
        bf16x8 b1 = *(const bf16x8*)(qb1);

        for (int ks = 0; ks < nk; ++ks) {
            bf16x8 nb0 = b0, nb1 = b1;
            if (ks + 1 < nk) {
                nb0 = *(const bf16x8*)(qb0 + (ks + 1) * 32);
                nb1 = *(const bf16x8*)(qb1 + (ks + 1) * 32);
            }
            bf16x8 a[2];
#pragma unroll
            for (int m = 0; m < 2; ++m) {
                int r = m * 16 + col;
                int e = (r * FDIM + ks * 32 + kg * 8) ^ ((r & 15) << 3);
                a[m] = *(const bf16x8*)(xs + e);
            }
#pragma unroll
            for (int m = 0; m < 2; ++m) {
                acc[0][m] = __builtin_amdgcn_mfma_f32_16x16x32_bf16(a[m], b0, acc[0][m], 0, 0, 0);
                acc[1][m] = __builtin_amdgcn_mfma_f32_16x16x32_bf16(a[m], b1, acc[1][m], 0, 0, 0);
            }
            b0 = nb0; b1 = nb1;
        }

        // epilogue: rs += xQ_frag * x  (D layout: col = lane&15, row = kg*4 + j)
#pragma unroll
        for (int m = 0; m < 2; ++m) {
#pragma unroll
            for (int j = 0; j < 4; ++j) {
                int r  = m * 16 + kg * 4 + j;
                int e0 = (r * FDIM + c0 + col)      ^ ((r & 15) << 3);
                int e1 = (r * FDIM + c0 + 16 + col) ^ ((r & 15) << 3);
                rs[m][j] += acc[0][m][j] * (float)xs[e0]
                          + acc[1][m][j] * (float)xs[e1];
            }
        }
    }

    // ---- reduce: 16 lanes (same kg) hold different cols of the same rows ----
#pragma unroll
    for (int m = 0; m < 2; ++m) {
#pragma unroll
        for (int j = 0; j < 4; ++j) {
            float v2 = rs[m][j];
            v2 += __shfl_xor(v2, 1);
            v2 += __shfl_xor(v2, 2);
            v2 += __shfl_xor(v2, 4);
            v2 += __shfl_xor(v2, 8);
            rs[m][j] = v2;
        }
    }
    if (col == 0) {
#pragma unroll
        for (int m = 0; m < 2; ++m)
#pragma unroll
            for (int j = 0; j < 4; ++j)
                rsum[w][m * 16 + kg * 4 + j] = rs[m][j];
    }
    __syncthreads();

    if (tid < BM) {
        float s = 0.0f;
#pragma unroll
        for (int ww = 0; ww < 4; ++ww) s += rsum[ww][tid];
        out[blk + tid] = s;
    }
}

extern "C" void kernel_launch(void* const* d_in, const int* in_sizes, int n_in,
                              void* d_out, int out_size, void* d_ws, size_t ws_size,
                              hipStream_t stream) {
    const float* x = (const float*)d_in[0];
    const float* Q = (const float*)d_in[1];
    float* out = (float*)d_out;
    bf16_t* Qt = (bf16_t*)d_ws;        // needs 512*512*2 = 512 KB scratch

    const int B = in_sizes[0] / FDIM;  // 131072

    dim3 tgrid(FDIM / 32, FDIM / 32);
    qtrans_kernel<<<tgrid, 256, 0, stream>>>(Q, Qt);
    bilinear_kernel<<<B / BM, NTHR, 0, stream>>>(x, Qt, out);
}